// Round 11
// baseline (109.236 us; speedup 1.0000x reference)
//
#include <hip/hip_runtime.h>
#include <math.h>

// TransferNet: BSZ=8, E=40000, D=128, R=512, NUM_STEPS=2, K=3, DEG=64
#define BSZ 8
#define E_ENT 40000
#define D_DIM 128
#define K_TOP 3
#define DEG 64
#define M_TRI (K_TOP * DEG)   // 192
#define D3 (3 * D_DIM)        // 384
#define NCH 40                // chunks per row for dense top-1
#define CHUNK 1000            // NCH * CHUNK == E_ENT

// prep block-role ranges (256 threads each)
#define PZ 313                // 313*256 float4 >= 80000 (zero d_out)
#define PT_END (PZ + 192)     // quad-pack W_ih: 192*256 = 49152 elems
#define PC_END (PT_END + 16)  // cq: 2 steps x 8 rows
#define PS_END (PC_END + 320) // stage-A: 8 rows x 40 chunks

typedef unsigned long long ull;

__device__ __forceinline__ float sigmoidf_(float x) { return 1.0f / (1.0f + expf(-x)); }

// Key preserves jax.lax.top_k order for v >= 0: value desc, tie -> lower index.
__device__ __forceinline__ ull make_key(float v, int idx) {
    return ((ull)__float_as_uint(v) << 32) |
           (ull)(0xFFFFFFFFu - (unsigned int)idx);
}
__device__ __forceinline__ int key_idx(ull k) {
    return (int)(0xFFFFFFFFu - (unsigned int)(k & 0xFFFFFFFFull));
}
__device__ __forceinline__ float key_val(ull k) {
    return __uint_as_float((unsigned int)(k >> 32));
}

// ---------------------------------------------------------------------------
// prep: zero d_out + tickets | quad-pack W_ih | cq GEMV | top-1 stage A
// WQ float4 layout: WQ4[(kkg*3+gate)*128+d] = W_ih[gate*128+d][4kkg..4kkg+3]
// ---------------------------------------------------------------------------
__global__ __launch_bounds__(256) void prep_kernel(
        const float* __restrict__ start,
        const float* __restrict__ rel_emb,
        const float* __restrict__ step_W,
        const float* __restrict__ step_b,
        const int* __restrict__ query,
        const float* __restrict__ W_ih,
        float* __restrict__ WQ,
        float* __restrict__ cq,
        ull* __restrict__ keysA,
        int* __restrict__ cnt,
        float* __restrict__ out) {
    int blk = blockIdx.x, tid = threadIdx.x;
    __shared__ float xs[D_DIM];
    __shared__ ull red[256];
    if (blk < PZ) {
        if (blk == 0 && tid < 16) cnt[tid] = 0;    // step0/step1 tickets
        int i = blk * 256 + tid;
        if (i < (BSZ * E_ENT) / 4) ((float4*)out)[i] = float4{0.f, 0.f, 0.f, 0.f};
    } else if (blk < PT_END) {
        int i = (blk - PZ) * 256 + tid;            // < 49152
        int o = i >> 7, kk = i & 127;              // W_ih[o][kk]
        WQ[((((kk >> 2) * 3 + (o >> 7)) * 128 + (o & 127)) << 2) + (kk & 3)] = W_ih[i];
    } else if (blk < PC_END) {
        int g = blk - PT_END;
        int t = g >> 3, b = g & 7;
        if (tid < D_DIM) xs[tid] = rel_emb[query[b] * D_DIM + tid];
        __syncthreads();
        if (tid < D_DIM) {
            float acc = step_b[t * D_DIM + tid];
            const float* W = step_W + t * D_DIM * D_DIM;
            for (int k = 0; k < D_DIM; k++) acc += xs[k] * W[k * D_DIM + tid];
            cq[(t * BSZ + b) * D_DIM + tid] = tanhf(acc);
        }
    } else {
        int g = blk - PC_END;
        int b = g / NCH, c = g % NCH;
        const float4* row4 = (const float4*)(start + (size_t)b * E_ENT) + c * (CHUNK / 4);
        int base = c * CHUNK;
        ull best = 0ull;
        if (tid < CHUNK / 4) {
            float4 v = row4[tid];
            int idx = base + tid * 4;
            ull k0 = make_key(v.x, idx);
            ull k1 = make_key(v.y, idx + 1);
            ull k2 = make_key(v.z, idx + 2);
            ull k3 = make_key(v.w, idx + 3);
            best = k0;
            if (k1 > best) best = k1;
            if (k2 > best) best = k2;
            if (k3 > best) best = k3;
        }
        red[tid] = best;
        __syncthreads();
        for (int s = 128; s > 0; s >>= 1) {
            if (tid < s && red[tid + s] > red[tid]) red[tid] = red[tid + s];
            __syncthreads();
        }
        if (tid == 0) keysA[b * NCH + c] = red[0];
    }
}

// ---------------------------------------------------------------------------
// step0: 512 blocks (b*64+j) x 128 threads.  Fused 40-key stage-B top-1 +
// one GRU cell (h == 0) per block.  The LAST block per b (ticket) also runs
// the "mid" phase: candidate top-3, h[k], gh[k] = h @ W_hh^T + b_hh.
// ---------------------------------------------------------------------------
__global__ __launch_bounds__(128) void step0_kernel(
        const ull* __restrict__ keysA,
        const float* __restrict__ cq,        // t=0 slice
        const float* __restrict__ rel_emb,
        const int* __restrict__ kb_triple,
        const int* __restrict__ kb_range,
        const float* __restrict__ WQ,
        const float* __restrict__ W_hh,
        const float* __restrict__ b_ih,
        const float* __restrict__ b_hh,
        const float* __restrict__ cls_w,
        const float* __restrict__ cls_b,
        float* __restrict__ feat,
        int* __restrict__ objs,
        float* __restrict__ p0,
        int* __restrict__ cnt0,
        int* __restrict__ pick_i,
        float* __restrict__ pick_v,
        float* __restrict__ hvec,
        float* __restrict__ gh) {
    int blk = blockIdx.x, tid = threadIdx.x;
    int b = blk >> 6, j = blk & 63;
    int d = tid;  // 128

    __shared__ ull kred[64];
    __shared__ __align__(16) float s_x[D_DIM];
    __shared__ float red[D_DIM];
    __shared__ int s_last;
    __shared__ int s_so[DEG];
    __shared__ float s_sp[DEG];
    __shared__ int s_pi[K_TOP];
    __shared__ float s_pv[K_TOP];
    __shared__ __align__(16) float s_h[K_TOP][D_DIM];

    if (d < 64) kred[d] = (d < NCH) ? keysA[b * NCH + d] : 0ull;
    __syncthreads();
    for (int s = 32; s > 0; s >>= 1) {
        if (d < s && kred[d + s] > kred[d]) kred[d] = kred[d + s];
        __syncthreads();
    }
    int ent = key_idx(kred[0]);
    float sub_p = key_val(kred[0]);
    int lo = kb_range[2 * ent], hi = kb_range[2 * ent + 1];
    int tri = lo + j;
    bool vj = tri < hi;
    int tu = vj ? tri : 0;
    int obj = kb_triple[3 * tu + 1];
    int rel = kb_triple[3 * tu + 2];
    s_x[d] = rel_emb[rel * D_DIM + d];
    __syncthreads();

    const float4* Wq = (const float4*)WQ;
    const float4* x4p = (const float4*)s_x;
    float ir = b_ih[d], iz = b_ih[D_DIM + d], inn = b_ih[2 * D_DIM + d];
    #pragma unroll 4
    for (int kkg = 0; kkg < 32; kkg++) {
        float4 x4 = x4p[kkg];
        float4 wr = Wq[(kkg * 3 + 0) * 128 + d];
        float4 wz = Wq[(kkg * 3 + 1) * 128 + d];
        float4 wn = Wq[(kkg * 3 + 2) * 128 + d];
        ir += x4.x * wr.x + x4.y * wr.y + x4.z * wr.z + x4.w * wr.w;
        iz += x4.x * wz.x + x4.y * wz.y + x4.z * wz.z + x4.w * wz.w;
        inn += x4.x * wn.x + x4.y * wn.y + x4.z * wn.z + x4.w * wn.w;
    }
    float r = sigmoidf_(ir + b_hh[d]);
    float z = sigmoidf_(iz + b_hh[D_DIM + d]);
    float n = tanhf(inn + r * b_hh[2 * D_DIM + d]);
    float trans = (1.f - z) * n;  // h == 0 at step 0

    red[d] = trans * cq[b * D_DIM + d] * cls_w[d];
    __syncthreads();
    for (int s = 64; s > 0; s >>= 1) {
        if (d < s) red[d] += red[d + s];
        __syncthreads();
    }
    float prob = sigmoidf_(red[0] + cls_b[0]);
    float obj_p = vj ? sub_p * prob : 0.f;

    feat[((size_t)b * DEG + j) * D_DIM + d] = trans * obj_p;
    if (d == 0) { objs[b * DEG + j] = obj; p0[b * DEG + j] = obj_p; }

    // ---- ticket: last block per b runs the mid phase ----------------------
    __syncthreads();
    if (tid == 0) {
        __threadfence();
        s_last = (atomicAdd(&cnt0[b], 1) == DEG - 1);
    }
    __syncthreads();
    if (!s_last) return;
    __threadfence();  // acquire: all step0 records for b visible

    if (tid < DEG) { s_so[tid] = objs[b * DEG + tid]; s_sp[tid] = p0[b * DEG + tid]; }
    __syncthreads();

    // candidate top-3 (aggregate dups ascending = jax order, norm, 3-pass)
    ull mykey = 0ull; int myobj = -1;
    if (tid < DEG) {
        myobj = s_so[tid];
        float v = 0.f;
        for (int i = 0; i < DEG; i++) if (s_so[i] == myobj) v += s_sp[i];
        v = v / fmaxf(v, 1.f);
        mykey = make_key(v, myobj);
    }
    for (int p = 0; p < K_TOP; p++) {
        ull k2 = mykey;
        for (int q = 0; q < p; q++) if (myobj == s_pi[q]) k2 = 0ull;
        if (tid < 64) kred[tid] = k2;
        __syncthreads();
        for (int s = 32; s > 0; s >>= 1) {
            if (tid < s && kred[tid + s] > kred[tid]) kred[tid] = kred[tid + s];
            __syncthreads();
        }
        if (tid == 0) {
            int idx = key_idx(kred[0]);
            float val = key_val(kred[0]);
            if (idx < 0 || idx >= E_ENT) { idx = p; val = 0.f; }  // <3 positives
            s_pi[p] = idx; s_pv[p] = val;
        }
        __syncthreads();
    }
    if (tid < K_TOP) { pick_i[b * K_TOP + tid] = s_pi[tid]; pick_v[b * K_TOP + tid] = s_pv[tid]; }

    // h[k][d]: one feat pass, three masked accumulators
    {
        float h0 = 0.f, h1 = 0.f, h2 = 0.f;
        const float* fb = feat + (size_t)b * DEG * D_DIM + d;
        int e0 = s_pi[0], e1 = s_pi[1], e2 = s_pi[2];
        for (int m = 0; m < DEG; m++) {
            float f = fb[m * D_DIM];
            int o = s_so[m];
            h0 += (o == e0) ? f : 0.f;
            h1 += (o == e1) ? f : 0.f;
            h2 += (o == e2) ? f : 0.f;
        }
        s_h[0][d] = h0; s_h[1][d] = h1; s_h[2][d] = h2;
        hvec[((size_t)b * K_TOP + 0) * D_DIM + d] = h0;
        hvec[((size_t)b * K_TOP + 1) * D_DIM + d] = h1;
        hvec[((size_t)b * K_TOP + 2) * D_DIM + d] = h2;
    }
    __syncthreads();

    // gh[k][o] = b_hh[o] + sum_kk h[k][kk] * W_hh[o][kk]; thread -> 3 cols
    {
        const float4* h0 = (const float4*)s_h[0];
        const float4* h1 = (const float4*)s_h[1];
        const float4* h2 = (const float4*)s_h[2];
        for (int oi = 0; oi < 3; oi++) {
            int o = tid + oi * 128;
            const float4* Wh4 = (const float4*)(W_hh + (size_t)o * D_DIM);
            float bb = b_hh[o];
            float a0 = bb, a1 = bb, a2 = bb;
            #pragma unroll 4
            for (int kkg = 0; kkg < 32; kkg++) {
                float4 w = Wh4[kkg];
                float4 v0 = h0[kkg], v1 = h1[kkg], v2 = h2[kkg];
                a0 += v0.x * w.x + v0.y * w.y + v0.z * w.z + v0.w * w.w;
                a1 += v1.x * w.x + v1.y * w.y + v1.z * w.z + v1.w * w.w;
                a2 += v2.x * w.x + v2.y * w.y + v2.z * w.z + v2.w * w.w;
            }
            gh[((size_t)b * K_TOP + 0) * D3 + o] = a0;
            gh[((size_t)b * K_TOP + 1) * D3 + o] = a1;
            gh[((size_t)b * K_TOP + 2) * D3 + o] = a2;
        }
    }
}

// ---------------------------------------------------------------------------
// step1: 1536 blocks (b*192 + k*64 + j) x 128 threads.  Streamlined: reads
// precomputed pick/hvec/gh; WQ float4 ih-GEMV; classifier.  LAST block per b
// (ticket, target 192) aggregates the 192 records and writes dense output.
// ---------------------------------------------------------------------------
__global__ __launch_bounds__(128) void step1_kernel(
        const int* __restrict__ pick_i,
        const float* __restrict__ pick_v,
        const float* __restrict__ hvec,
        const float* __restrict__ gh,
        const float* __restrict__ cq,        // full cq; t=1 slice at [BSZ..)
        const float* __restrict__ rel_emb,
        const int* __restrict__ kb_triple,
        const int* __restrict__ kb_range,
        const float* __restrict__ WQ,
        const float* __restrict__ b_ih,
        const float* __restrict__ cls_w,
        const float* __restrict__ cls_b,
        int* __restrict__ obj1,
        float* __restrict__ p1,
        int* __restrict__ cnt1,
        float* __restrict__ out) {
    int blk = blockIdx.x, tid = threadIdx.x;
    int b = blk / M_TRI;
    int rem = blk % M_TRI;
    int k = rem >> 6, j = rem & 63;
    int d = tid;  // 128

    __shared__ __align__(16) float s_x[D_DIM];
    __shared__ float red[D_DIM];
    __shared__ int s_last;
    __shared__ int s_fo[M_TRI];
    __shared__ float s_fp[M_TRI];

    int ent = pick_i[b * K_TOP + k];
    float sub_p = pick_v[b * K_TOP + k];
    int lo = kb_range[2 * ent], hi = kb_range[2 * ent + 1];
    int tri = lo + j;
    bool vj = tri < hi;
    int tu = vj ? tri : 0;
    int obj = kb_triple[3 * tu + 1];
    int rel = kb_triple[3 * tu + 2];
    s_x[d] = rel_emb[rel * D_DIM + d];

    size_t hkbase = ((size_t)b * K_TOP + k) * D_DIM;
    size_t gbase = ((size_t)b * K_TOP + k) * D3;
    float hd = hvec[hkbase + d];
    float ghr = gh[gbase + d];
    float ghz = gh[gbase + D_DIM + d];
    float ghn = gh[gbase + 2 * D_DIM + d];
    __syncthreads();

    const float4* Wq = (const float4*)WQ;
    const float4* x4p = (const float4*)s_x;
    float ir = b_ih[d], iz = b_ih[D_DIM + d], inn = b_ih[2 * D_DIM + d];
    #pragma unroll 4
    for (int kkg = 0; kkg < 32; kkg++) {
        float4 x4 = x4p[kkg];
        float4 wr = Wq[(kkg * 3 + 0) * 128 + d];
        float4 wz = Wq[(kkg * 3 + 1) * 128 + d];
        float4 wn = Wq[(kkg * 3 + 2) * 128 + d];
        ir += x4.x * wr.x + x4.y * wr.y + x4.z * wr.z + x4.w * wr.w;
        iz += x4.x * wz.x + x4.y * wz.y + x4.z * wz.z + x4.w * wz.w;
        inn += x4.x * wn.x + x4.y * wn.y + x4.z * wn.z + x4.w * wn.w;
    }
    float r = sigmoidf_(ir + ghr);
    float z = sigmoidf_(iz + ghz);
    float n = tanhf(inn + r * ghn);
    float trans = (1.f - z) * n + z * hd;

    red[d] = trans * cq[(BSZ + b) * D_DIM + d] * cls_w[d];  // t=1 slice
    __syncthreads();
    for (int s = 64; s > 0; s >>= 1) {
        if (d < s) red[d] += red[d + s];
        __syncthreads();
    }
    float prob = sigmoidf_(red[0] + cls_b[0]);
    if (d == 0) {
        int idx = b * M_TRI + rem;
        obj1[idx] = obj;
        p1[idx] = vj ? sub_p * prob : 0.f;
    }

    // ---- ticket: last block per b finalizes -------------------------------
    __syncthreads();
    if (tid == 0) {
        __threadfence();
        s_last = (atomicAdd(&cnt1[b], 1) == M_TRI - 1);
    }
    __syncthreads();
    if (!s_last) return;
    __threadfence();  // acquire: all records for b visible

    for (int m = tid; m < M_TRI; m += 128) {
        s_fo[m] = obj1[b * M_TRI + m];
        s_fp[m] = p1[b * M_TRI + m];
    }
    __syncthreads();
    for (int m = tid; m < M_TRI; m += 128) {
        int o = s_fo[m];
        float vv = 0.f;
        for (int i = 0; i < M_TRI; i++) if (s_fo[i] == o) vv += s_fp[i];
        out[(size_t)b * E_ENT + o] = vv / fmaxf(vv, 1.f);
    }
}

extern "C" void kernel_launch(void* const* d_in, const int* in_sizes, int n_in,
                              void* d_out, int out_size, void* d_ws, size_t ws_size,
                              hipStream_t stream) {
    const float* start    = (const float*)d_in[0];
    const float* rel_emb  = (const float*)d_in[1];
    const float* step_W   = (const float*)d_in[2];
    const float* step_b   = (const float*)d_in[3];
    const float* W_ih     = (const float*)d_in[4];
    const float* W_hh     = (const float*)d_in[5];
    const float* b_ih     = (const float*)d_in[6];
    const float* b_hh     = (const float*)d_in[7];
    const float* cls_w    = (const float*)d_in[8];
    const float* cls_b    = (const float*)d_in[9];
    const int*   query    = (const int*)d_in[10];
    const int*   kb_triple = (const int*)d_in[11];
    const int*   kb_range  = (const int*)d_in[12];
    float* out = (float*)d_out;

    char* ws = (char*)d_ws;
    float* WQ    = (float*)ws;  ws += (size_t)D3 * D_DIM * sizeof(float);
    float* cq    = (float*)ws;  ws += (size_t)2 * BSZ * D_DIM * sizeof(float);
    float* feat  = (float*)ws;  ws += (size_t)BSZ * DEG * D_DIM * sizeof(float);
    int*   objs  = (int*)ws;    ws += (size_t)BSZ * DEG * sizeof(int);
    float* p0    = (float*)ws;  ws += (size_t)BSZ * DEG * sizeof(float);
    ull*   keysA = (ull*)ws;    ws += (size_t)BSZ * NCH * sizeof(ull);
    int*   obj1  = (int*)ws;    ws += (size_t)BSZ * M_TRI * sizeof(int);
    float* p1    = (float*)ws;  ws += (size_t)BSZ * M_TRI * sizeof(float);
    int*   cnt   = (int*)ws;    ws += (size_t)16 * sizeof(int);
    int*   pick_i = (int*)ws;   ws += (size_t)BSZ * K_TOP * sizeof(int);
    float* pick_v = (float*)ws; ws += (size_t)BSZ * K_TOP * sizeof(float);
    float* hvec  = (float*)ws;  ws += (size_t)BSZ * K_TOP * D_DIM * sizeof(float);
    float* gh    = (float*)ws;  ws += (size_t)BSZ * K_TOP * D3 * sizeof(float);
    int* cnt0 = cnt;
    int* cnt1 = cnt + 8;

    prep_kernel<<<PS_END, 256, 0, stream>>>(
        start, rel_emb, step_W, step_b, query, W_ih,
        WQ, cq, keysA, cnt, out);

    step0_kernel<<<BSZ * DEG, 128, 0, stream>>>(
        keysA, cq, rel_emb, kb_triple, kb_range,
        WQ, W_hh, b_ih, b_hh, cls_w, cls_b,
        feat, objs, p0, cnt0, pick_i, pick_v, hvec, gh);

    step1_kernel<<<BSZ * M_TRI, 128, 0, stream>>>(
        pick_i, pick_v, hvec, gh, cq, rel_emb, kb_triple, kb_range,
        WQ, b_ih, cls_w, cls_b,
        obj1, p1, cnt1, out);
}

// Round 12
// 56.191 us; speedup vs baseline: 1.9440x; 1.9440x over previous
//
#include <hip/hip_runtime.h>
#include <math.h>

// TransferNet: BSZ=8, E=40000, D=128, R=512, NUM_STEPS=2, K=3, DEG=64
#define BSZ 8
#define E_ENT 40000
#define D_DIM 128
#define K_TOP 3
#define DEG 64
#define M_TRI (K_TOP * DEG)   // 192
#define D3 (3 * D_DIM)        // 384
#define NCH 40                // chunks per row for dense top-1
#define CHUNK 1000            // NCH * CHUNK == E_ENT

// prep block-role ranges (256 threads each)
#define PZ 313                // 313*256 float4 >= 80000 (zero d_out)
#define PT_END (PZ + 192)     // quad-pack W_ih: 192*256 = 49152 elems
#define PC_END (PT_END + 16)  // cq: 2 steps x 8 rows
#define PS_END (PC_END + 320) // stage-A: 8 rows x 40 chunks

typedef unsigned long long ull;

__device__ __forceinline__ float sigmoidf_(float x) { return 1.0f / (1.0f + expf(-x)); }

// Key preserves jax.lax.top_k order for v >= 0: value desc, tie -> lower index.
__device__ __forceinline__ ull make_key(float v, int idx) {
    return ((ull)__float_as_uint(v) << 32) |
           (ull)(0xFFFFFFFFu - (unsigned int)idx);
}
__device__ __forceinline__ int key_idx(ull k) {
    return (int)(0xFFFFFFFFu - (unsigned int)(k & 0xFFFFFFFFull));
}
__device__ __forceinline__ float key_val(ull k) {
    return __uint_as_float((unsigned int)(k >> 32));
}

// ---------------------------------------------------------------------------
// prep: zero d_out | quad-pack W_ih | cq GEMV | top-1 stage A
// WQ float4 layout: WQ4[(kkg*3+gate)*128+d] = W_ih[gate*128+d][4kkg..4kkg+3]
// ---------------------------------------------------------------------------
__global__ __launch_bounds__(256) void prep_kernel(
        const float* __restrict__ start,
        const float* __restrict__ rel_emb,
        const float* __restrict__ step_W,
        const float* __restrict__ step_b,
        const int* __restrict__ query,
        const float* __restrict__ W_ih,
        float* __restrict__ WQ,
        float* __restrict__ cq,
        ull* __restrict__ keysA,
        float* __restrict__ out) {
    int blk = blockIdx.x, tid = threadIdx.x;
    __shared__ float xs[D_DIM];
    __shared__ ull red[256];
    if (blk < PZ) {
        int i = blk * 256 + tid;
        if (i < (BSZ * E_ENT) / 4) ((float4*)out)[i] = float4{0.f, 0.f, 0.f, 0.f};
    } else if (blk < PT_END) {
        int i = (blk - PZ) * 256 + tid;            // < 49152
        int o = i >> 7, kk = i & 127;              // W_ih[o][kk]
        WQ[((((kk >> 2) * 3 + (o >> 7)) * 128 + (o & 127)) << 2) + (kk & 3)] = W_ih[i];
    } else if (blk < PC_END) {
        int g = blk - PT_END;
        int t = g >> 3, b = g & 7;
        if (tid < D_DIM) xs[tid] = rel_emb[query[b] * D_DIM + tid];
        __syncthreads();
        if (tid < D_DIM) {
            float acc = step_b[t * D_DIM + tid];
            const float* W = step_W + t * D_DIM * D_DIM;
            for (int k = 0; k < D_DIM; k++) acc += xs[k] * W[k * D_DIM + tid];
            cq[(t * BSZ + b) * D_DIM + tid] = tanhf(acc);
        }
    } else {
        int g = blk - PC_END;
        int b = g / NCH, c = g % NCH;
        const float4* row4 = (const float4*)(start + (size_t)b * E_ENT) + c * (CHUNK / 4);
        int base = c * CHUNK;
        ull best = 0ull;
        if (tid < CHUNK / 4) {
            float4 v = row4[tid];
            int idx = base + tid * 4;
            ull k0 = make_key(v.x, idx);
            ull k1 = make_key(v.y, idx + 1);
            ull k2 = make_key(v.z, idx + 2);
            ull k3 = make_key(v.w, idx + 3);
            best = k0;
            if (k1 > best) best = k1;
            if (k2 > best) best = k2;
            if (k3 > best) best = k3;
        }
        red[tid] = best;
        __syncthreads();
        for (int s = 128; s > 0; s >>= 1) {
            if (tid < s && red[tid + s] > red[tid]) red[tid] = red[tid + s];
            __syncthreads();
        }
        if (tid == 0) keysA[b * NCH + c] = red[0];
    }
}

// ---------------------------------------------------------------------------
// step0: 512 blocks (b*64+j) x 128 threads.  Fused 40-key stage-B top-1 +
// one GRU cell (h == 0).  No atomics, no fences.
// ---------------------------------------------------------------------------
__global__ __launch_bounds__(128) void step0_kernel(
        const ull* __restrict__ keysA,
        const float* __restrict__ cq,        // t=0 slice
        const float* __restrict__ rel_emb,
        const int* __restrict__ kb_triple,
        const int* __restrict__ kb_range,
        const float* __restrict__ WQ,
        const float* __restrict__ b_ih,
        const float* __restrict__ b_hh,
        const float* __restrict__ cls_w,
        const float* __restrict__ cls_b,
        float* __restrict__ feat,
        int* __restrict__ objs,
        float* __restrict__ p0) {
    int blk = blockIdx.x, tid = threadIdx.x;
    int b = blk >> 6, j = blk & 63;
    int d = tid;  // 128

    __shared__ ull kred[64];
    __shared__ __align__(16) float s_x[D_DIM];
    __shared__ float s_part[2];
    __shared__ float s_prob;

    if (d < 64) kred[d] = (d < NCH) ? keysA[b * NCH + d] : 0ull;
    __syncthreads();
    for (int s = 32; s > 0; s >>= 1) {
        if (d < s && kred[d + s] > kred[d]) kred[d] = kred[d + s];
        __syncthreads();
    }
    int ent = key_idx(kred[0]);
    float sub_p = key_val(kred[0]);
    int lo = kb_range[2 * ent], hi = kb_range[2 * ent + 1];
    int tri = lo + j;
    bool vj = tri < hi;
    int tu = vj ? tri : 0;
    int obj = kb_triple[3 * tu + 1];
    int rel = kb_triple[3 * tu + 2];
    s_x[d] = rel_emb[rel * D_DIM + d];
    __syncthreads();

    const float4* Wq = (const float4*)WQ;
    const float4* x4p = (const float4*)s_x;
    float ir = b_ih[d], iz = b_ih[D_DIM + d], inn = b_ih[2 * D_DIM + d];
    #pragma unroll 4
    for (int kkg = 0; kkg < 32; kkg++) {
        float4 x4 = x4p[kkg];
        float4 wr = Wq[(kkg * 3 + 0) * 128 + d];
        float4 wz = Wq[(kkg * 3 + 1) * 128 + d];
        float4 wn = Wq[(kkg * 3 + 2) * 128 + d];
        ir += x4.x * wr.x + x4.y * wr.y + x4.z * wr.z + x4.w * wr.w;
        iz += x4.x * wz.x + x4.y * wz.y + x4.z * wz.z + x4.w * wz.w;
        inn += x4.x * wn.x + x4.y * wn.y + x4.z * wn.z + x4.w * wn.w;
    }
    float r = sigmoidf_(ir + b_hh[d]);
    float z = sigmoidf_(iz + b_hh[D_DIM + d]);
    float n = tanhf(inn + r * b_hh[2 * D_DIM + d]);
    float trans = (1.f - z) * n;  // h == 0 at step 0

    float v = trans * cq[b * D_DIM + d] * cls_w[d];
    for (int off = 32; off > 0; off >>= 1) v += __shfl_xor(v, off, 64);
    if ((d & 63) == 0) s_part[d >> 6] = v;
    __syncthreads();
    if (d == 0) s_prob = sigmoidf_(s_part[0] + s_part[1] + cls_b[0]);
    __syncthreads();
    float obj_p = vj ? sub_p * s_prob : 0.f;

    feat[((size_t)b * DEG + j) * D_DIM + d] = trans * obj_p;
    if (d == 0) { objs[b * DEG + j] = obj; p0[b * DEG + j] = obj_p; }
}

// ---------------------------------------------------------------------------
// mid: per-b (8 blocks x 384 threads): candidate top-3 over step-0 records
// (aggregate dups ascending = jax scatter order, normalize max(v,1), 3-pass
// exclusion) + h[b][k][:] (unconditional masked sum) + gh = h @ W_hh^T + b_hh.
// ---------------------------------------------------------------------------
__global__ __launch_bounds__(384) void mid_kernel(
        const int* __restrict__ objs,
        const float* __restrict__ p0,
        const float* __restrict__ feat,
        const float* __restrict__ W_hh,
        const float* __restrict__ b_hh,
        int* __restrict__ pick_i,
        float* __restrict__ pick_v,
        float* __restrict__ hvec,
        float* __restrict__ gh) {
    int b = blockIdx.x, tid = threadIdx.x;  // 384 threads

    __shared__ int s_so[DEG];
    __shared__ float s_sp[DEG];
    __shared__ ull kred[64];
    __shared__ int s_pi[K_TOP];
    __shared__ float s_pv[K_TOP];
    __shared__ __align__(16) float s_h[K_TOP][D_DIM];

    if (tid < DEG) { s_so[tid] = objs[b * DEG + tid]; s_sp[tid] = p0[b * DEG + tid]; }
    __syncthreads();

    ull mykey = 0ull; int myobj = -1;
    if (tid < DEG) {
        myobj = s_so[tid];
        float v = 0.f;
        for (int i = 0; i < DEG; i++) if (s_so[i] == myobj) v += s_sp[i];
        v = v / fmaxf(v, 1.f);
        mykey = make_key(v, myobj);
    }
    for (int p = 0; p < K_TOP; p++) {
        ull k2 = mykey;
        for (int q = 0; q < p; q++) if (myobj == s_pi[q]) k2 = 0ull;
        if (tid < 64) kred[tid] = k2;
        __syncthreads();
        for (int s = 32; s > 0; s >>= 1) {
            if (tid < s && kred[tid + s] > kred[tid]) kred[tid] = kred[tid + s];
            __syncthreads();
        }
        if (tid == 0) {
            int idx = key_idx(kred[0]);
            float val = key_val(kred[0]);
            if (idx < 0 || idx >= E_ENT) { idx = p; val = 0.f; }  // <3 positives
            s_pi[p] = idx; s_pv[p] = val;
        }
        __syncthreads();
    }
    if (tid < K_TOP) { pick_i[b * K_TOP + tid] = s_pi[tid]; pick_v[b * K_TOP + tid] = s_pv[tid]; }

    {   // h[b][k][d]: unconditional loads, arithmetic mask
        int k = tid >> 7, d = tid & 127;
        int ent = s_pi[k];
        float hd = 0.f;
        const float* fb = feat + (size_t)b * DEG * D_DIM + d;
        for (int m = 0; m < DEG; m++) {
            float f = fb[m * D_DIM];
            hd += (s_so[m] == ent) ? f : 0.f;
        }
        s_h[k][d] = hd;
        hvec[((size_t)b * K_TOP + k) * D_DIM + d] = hd;
    }
    __syncthreads();

    {   // gh[b][k][o] = b_hh[o] + sum_kk h[k][kk] * W_hh[o][kk]
        int o = tid;
        const float4* Wh4 = (const float4*)W_hh + (size_t)o * 32;
        const float4* h0 = (const float4*)s_h[0];
        const float4* h1 = (const float4*)s_h[1];
        const float4* h2 = (const float4*)s_h[2];
        float a0 = b_hh[o], a1 = a0, a2 = a0;
        #pragma unroll 4
        for (int kkg = 0; kkg < 32; kkg++) {
            float4 w = Wh4[kkg];
            float4 v0 = h0[kkg], v1 = h1[kkg], v2 = h2[kkg];
            a0 += v0.x * w.x + v0.y * w.y + v0.z * w.z + v0.w * w.w;
            a1 += v1.x * w.x + v1.y * w.y + v1.z * w.z + v1.w * w.w;
            a2 += v2.x * w.x + v2.y * w.y + v2.z * w.z + v2.w * w.w;
        }
        gh[((size_t)b * K_TOP + 0) * D3 + o] = a0;
        gh[((size_t)b * K_TOP + 1) * D3 + o] = a1;
        gh[((size_t)b * K_TOP + 2) * D3 + o] = a2;
    }
}

// ---------------------------------------------------------------------------
// step1: 1536 blocks (b*192 + k*64 + j) x 128 threads.  Streamlined: reads
// precomputed pick/hvec/gh; WQ float4 ih-GEMV; classifier.  No atomics.
// ---------------------------------------------------------------------------
__global__ __launch_bounds__(128) void step1_kernel(
        const int* __restrict__ pick_i,
        const float* __restrict__ pick_v,
        const float* __restrict__ hvec,
        const float* __restrict__ gh,
        const float* __restrict__ cq,        // full cq; t=1 slice at [BSZ..)
        const float* __restrict__ rel_emb,
        const int* __restrict__ kb_triple,
        const int* __restrict__ kb_range,
        const float* __restrict__ WQ,
        const float* __restrict__ b_ih,
        const float* __restrict__ cls_w,
        const float* __restrict__ cls_b,
        int* __restrict__ obj1,
        float* __restrict__ p1) {
    int blk = blockIdx.x, tid = threadIdx.x;
    int b = blk / M_TRI;
    int rem = blk % M_TRI;
    int k = rem >> 6, j = rem & 63;
    int d = tid;  // 128

    __shared__ __align__(16) float s_x[D_DIM];
    __shared__ float s_part[2];
    __shared__ float s_prob;

    int ent = pick_i[b * K_TOP + k];
    float sub_p = pick_v[b * K_TOP + k];
    int lo = kb_range[2 * ent], hi = kb_range[2 * ent + 1];
    int tri = lo + j;
    bool vj = tri < hi;
    int tu = vj ? tri : 0;
    int obj = kb_triple[3 * tu + 1];
    int rel = kb_triple[3 * tu + 2];
    s_x[d] = rel_emb[rel * D_DIM + d];

    size_t hkbase = ((size_t)b * K_TOP + k) * D_DIM;
    size_t gbase = ((size_t)b * K_TOP + k) * D3;
    float hd = hvec[hkbase + d];
    float ghr = gh[gbase + d];
    float ghz = gh[gbase + D_DIM + d];
    float ghn = gh[gbase + 2 * D_DIM + d];
    __syncthreads();

    const float4* Wq = (const float4*)WQ;
    const float4* x4p = (const float4*)s_x;
    float ir = b_ih[d], iz = b_ih[D_DIM + d], inn = b_ih[2 * D_DIM + d];
    #pragma unroll 4
    for (int kkg = 0; kkg < 32; kkg++) {
        float4 x4 = x4p[kkg];
        float4 wr = Wq[(kkg * 3 + 0) * 128 + d];
        float4 wz = Wq[(kkg * 3 + 1) * 128 + d];
        float4 wn = Wq[(kkg * 3 + 2) * 128 + d];
        ir += x4.x * wr.x + x4.y * wr.y + x4.z * wr.z + x4.w * wr.w;
        iz += x4.x * wz.x + x4.y * wz.y + x4.z * wz.z + x4.w * wz.w;
        inn += x4.x * wn.x + x4.y * wn.y + x4.z * wn.z + x4.w * wn.w;
    }
    float r = sigmoidf_(ir + ghr);
    float z = sigmoidf_(iz + ghz);
    float n = tanhf(inn + r * ghn);
    float trans = (1.f - z) * n + z * hd;

    float v = trans * cq[(BSZ + b) * D_DIM + d] * cls_w[d];  // t=1 slice
    for (int off = 32; off > 0; off >>= 1) v += __shfl_xor(v, off, 64);
    if ((d & 63) == 0) s_part[d >> 6] = v;
    __syncthreads();
    if (d == 0) s_prob = sigmoidf_(s_part[0] + s_part[1] + cls_b[0]);
    __syncthreads();
    if (d == 0) {
        int idx = b * M_TRI + rem;
        obj1[idx] = obj;
        p1[idx] = vj ? sub_p * s_prob : 0.f;
    }
}

// ---------------------------------------------------------------------------
// finalize: aggregate the 192 (obj, p) records per row, write normalized
// values into the pre-zeroed dense output.  Duplicate threads write
// identical values -> deterministic, no atomics.  8 blocks x 192 threads.
// ---------------------------------------------------------------------------
__global__ void finalize_kernel(const int* __restrict__ obj1,
                                const float* __restrict__ p1,
                                float* __restrict__ out) {
    int b = blockIdx.x, m = threadIdx.x;  // 192
    __shared__ int so[M_TRI];
    __shared__ float sp[M_TRI];
    so[m] = obj1[b * M_TRI + m];
    sp[m] = p1[b * M_TRI + m];
    __syncthreads();
    int o = so[m];
    float v = 0.f;
    for (int i = 0; i < M_TRI; i++) if (so[i] == o) v += sp[i];
    out[(size_t)b * E_ENT + o] = v / fmaxf(v, 1.f);
}

extern "C" void kernel_launch(void* const* d_in, const int* in_sizes, int n_in,
                              void* d_out, int out_size, void* d_ws, size_t ws_size,
                              hipStream_t stream) {
    const float* start    = (const float*)d_in[0];
    const float* rel_emb  = (const float*)d_in[1];
    const float* step_W   = (const float*)d_in[2];
    const float* step_b   = (const float*)d_in[3];
    const float* W_ih     = (const float*)d_in[4];
    const float* W_hh     = (const float*)d_in[5];
    const float* b_ih     = (const float*)d_in[6];
    const float* b_hh     = (const float*)d_in[7];
    const float* cls_w    = (const float*)d_in[8];
    const float* cls_b    = (const float*)d_in[9];
    const int*   query    = (const int*)d_in[10];
    const int*   kb_triple = (const int*)d_in[11];
    const int*   kb_range  = (const int*)d_in[12];
    float* out = (float*)d_out;

    char* ws = (char*)d_ws;
    float* WQ    = (float*)ws;  ws += (size_t)D3 * D_DIM * sizeof(float);
    float* cq    = (float*)ws;  ws += (size_t)2 * BSZ * D_DIM * sizeof(float);
    float* feat  = (float*)ws;  ws += (size_t)BSZ * DEG * D_DIM * sizeof(float);
    int*   objs  = (int*)ws;    ws += (size_t)BSZ * DEG * sizeof(int);
    float* p0    = (float*)ws;  ws += (size_t)BSZ * DEG * sizeof(float);
    ull*   keysA = (ull*)ws;    ws += (size_t)BSZ * NCH * sizeof(ull);
    int*   obj1  = (int*)ws;    ws += (size_t)BSZ * M_TRI * sizeof(int);
    float* p1    = (float*)ws;  ws += (size_t)BSZ * M_TRI * sizeof(float);
    int*   pick_i = (int*)ws;   ws += (size_t)BSZ * K_TOP * sizeof(int);
    float* pick_v = (float*)ws; ws += (size_t)BSZ * K_TOP * sizeof(float);
    float* hvec  = (float*)ws;  ws += (size_t)BSZ * K_TOP * D_DIM * sizeof(float);
    float* gh    = (float*)ws;  ws += (size_t)BSZ * K_TOP * D3 * sizeof(float);

    prep_kernel<<<PS_END, 256, 0, stream>>>(
        start, rel_emb, step_W, step_b, query, W_ih,
        WQ, cq, keysA, out);

    step0_kernel<<<BSZ * DEG, 128, 0, stream>>>(
        keysA, cq, rel_emb, kb_triple, kb_range,
        WQ, b_ih, b_hh, cls_w, cls_b,
        feat, objs, p0);

    mid_kernel<<<BSZ, 384, 0, stream>>>(
        objs, p0, feat, W_hh, b_hh, pick_i, pick_v, hvec, gh);

    step1_kernel<<<BSZ * M_TRI, 128, 0, stream>>>(
        pick_i, pick_v, hvec, gh, cq, rel_emb, kb_triple, kb_range,
        WQ, b_ih, cls_w, cls_b,
        obj1, p1);

    finalize_kernel<<<BSZ, M_TRI, 0, stream>>>(obj1, p1, out);
}